// Round 10
// baseline (1002.588 us; speedup 1.0000x reference)
//
#include <hip/hip_runtime.h>
#include <hip/hip_bf16.h>
#include <math.h>

#define N_NODES 50000
#define N_EDGES 800000
#define EPS 1e-5f
#define SLOPE 0.2f

typedef unsigned int u32;
typedef unsigned short u16;
typedef float floatx4 __attribute__((ext_vector_type(4)));
typedef short short8_t __attribute__((ext_vector_type(8)));

__device__ __forceinline__ float bf2f(u16 v) {
    u32 u = ((u32)v) << 16;
    return __uint_as_float(u);
}
__device__ __forceinline__ u16 f2bf(float f) {
    u32 u = __float_as_uint(f);
    u32 r = (u + 0x7fffu + ((u >> 16) & 1u)) >> 16;  // RNE
    return (u16)r;
}
__device__ __forceinline__ float lo_bf(u32 v) { return __uint_as_float(v << 16); }
__device__ __forceinline__ float hi_bf(u32 v) { return __uint_as_float(v & 0xffff0000u); }
__device__ __forceinline__ float wred(float v) {
    #pragma unroll
    for (int off = 32; off > 0; off >>= 1) v += __shfl_xor(v, off, 64);
    return v;
}

// ---- M[k][l*4+h] = sum_c gat_ew[l][k][h*32+c] * gat_ae[l][h][c] ----
__global__ void k_M(const float* __restrict__ ew, const float* __restrict__ ae,
                    float* __restrict__ M) {
    int t = threadIdx.x;
    if (t >= 768) return;
    int k = t / 12, j = t % 12;
    int l = j >> 2, h = j & 3;
    const float* ewp = ew + l * 8192 + k * 128 + h * 32;
    const float* aep = ae + l * 128 + h * 32;
    float s = 0.f;
    #pragma unroll
    for (int c = 0; c < 32; c++) s += ewp[c] * aep[c];
    M[k * 12 + j] = s;
}

// ---- split-transpose 128x128 fp32 weights: wt[l][n][k] = bf16split(w[l][k][n]) ----
__global__ void k_convW(const float* __restrict__ w, u16* __restrict__ hi,
                        u16* __restrict__ lo, int total) {
    int i = blockIdx.x * 256 + threadIdx.x;
    if (i >= total) return;
    int l = i >> 14, r = i & 16383;
    int n = r >> 7, k = r & 127;
    float f = w[(size_t)l * 16384 + k * 128 + n];
    u16 hb = f2bf(f);
    hi[i] = hb;
    lo[i] = f2bf(f - bf2f(hb));
}

// ---- node preprocess: h = relu(LN(x @ np_w + np_b)) ; wave per node ----
__global__ __launch_bounds__(256) void k_node_pre(
        const float* __restrict__ x, const float* __restrict__ w,
        const float* __restrict__ b, const float* __restrict__ g,
        const float* __restrict__ be, float* __restrict__ h) {
    int wave = threadIdx.x >> 6, lane = threadIdx.x & 63;
    int n = blockIdx.x * 4 + wave;
    if (n >= N_NODES) return;
    const float* xr = x + (size_t)n * 16;
    float xv[16];
    #pragma unroll
    for (int k = 0; k < 16; k++) xv[k] = xr[k];
    int c0 = lane, c1 = lane + 64;
    float a0 = b[c0], a1 = b[c1];
    #pragma unroll
    for (int k = 0; k < 16; k++) {
        a0 = fmaf(xv[k], w[k * 128 + c0], a0);
        a1 = fmaf(xv[k], w[k * 128 + c1], a1);
    }
    float m = wred(a0 + a1) * (1.f / 128.f);
    float d0 = a0 - m, d1 = a1 - m;
    float v = wred(d0 * d0 + d1 * d1) * (1.f / 128.f);
    float rs = rsqrtf(v + EPS);
    float o0 = d0 * rs * g[c0] + be[c0];
    float o1 = d1 * rs * g[c1] + be[c1];
    h[(size_t)n * 128 + c0] = fmaxf(o0, 0.f);
    h[(size_t)n * 128 + c1] = fmaxf(o1, 0.f);
}

// ---- degree count + within-row rank (atomic return value, coalesced write) ----
__global__ void k_deg(const int* __restrict__ dst, int* __restrict__ deg,
                      int* __restrict__ rank) {
    int e = blockIdx.x * 256 + threadIdx.x;
    if (e < N_EDGES) rank[e] = atomicAdd(&deg[dst[e]], 1);
}

// ---- 3-phase exclusive scan -> rowptr ----
__global__ void k_scan1(const int* __restrict__ deg, int* __restrict__ incl,
                        int* __restrict__ bsum) {
    __shared__ int lds[1024];
    int i = blockIdx.x * 1024 + threadIdx.x;
    int v = (i < N_NODES) ? deg[i] : 0;
    lds[threadIdx.x] = v;
    __syncthreads();
    for (int off = 1; off < 1024; off <<= 1) {
        int t = (threadIdx.x >= off) ? lds[threadIdx.x - off] : 0;
        __syncthreads();
        lds[threadIdx.x] += t;
        __syncthreads();
    }
    if (i < N_NODES) incl[i] = lds[threadIdx.x];
    if (threadIdx.x == 1023) bsum[blockIdx.x] = lds[1023];
}
__global__ void k_scan2(int* __restrict__ bsum, int nb) {
    if (threadIdx.x == 0 && blockIdx.x == 0) {
        int run = 0;
        for (int i = 0; i < nb; i++) { int t = bsum[i]; bsum[i] = run; run += t; }
    }
}
__global__ void k_scan3(const int* __restrict__ incl, const int* __restrict__ bsum,
                        int* __restrict__ rowptr) {
    int i = blockIdx.x * 1024 + threadIdx.x;
    if (i < N_NODES) rowptr[i + 1] = incl[i] + bsum[blockIdx.x];
    if (i == 0) rowptr[0] = 0;
}

// ---- CSR slot fill: atomic-free scatter (slot = rowptr[dst] + rank[e]) ----
__global__ void k_fill(const int* __restrict__ ei, const int* __restrict__ rowptr,
                       const int* __restrict__ rank, int2* __restrict__ csr_se) {
    int e = blockIdx.x * 256 + threadIdx.x;
    if (e >= N_EDGES) return;
    int src = ei[e], dst = ei[N_EDGES + e];
    int slot = rowptr[dst] + rank[e];
    csr_se[slot] = make_int2(src, e);
}

// ---- edge preprocess + alphaE: 2 edges/thread, broadcast LDS (0 conflicts) ----
// Each sW4/sM4 b128 broadcast read feeds both edges' FMAs: LDS insts/edge
// halve; 2 csr_se + 4 ea loads in flight double memory-level parallelism.
__global__ __launch_bounds__(256) void k_edge_c(
        const int2* __restrict__ csr_se, const float* __restrict__ ea,
        const float* __restrict__ epw, const float* __restrict__ epb,
        const float* __restrict__ epg, const float* __restrict__ epbe,
        const float* __restrict__ M, int* __restrict__ csr_src,
        float* __restrict__ csr_aE) {
    __shared__ floatx4 sW4[128], sM4[192], sB4[16], sG4[16], sBe4[16];
    int tid = threadIdx.x;
    if (tid < 128) sW4[tid] = ((const floatx4*)epw)[tid];
    if (tid < 192) sM4[tid] = ((const floatx4*)M)[tid];
    if (tid < 16) sB4[tid] = ((const floatx4*)epb)[tid];
    if (tid >= 32 && tid < 48) sG4[tid - 32] = ((const floatx4*)epg)[tid - 32];
    if (tid >= 64 && tid < 80) sBe4[tid - 64] = ((const floatx4*)epbe)[tid - 64];
    __syncthreads();
    int s0 = blockIdx.x * 512 + tid;
    int s1 = s0 + 256;
    if (s0 >= N_EDGES) return;
    bool has1 = (s1 < N_EDGES);
    int2 seA = csr_se[s0];
    int2 seB = has1 ? csr_se[s1] : seA;
    float4 a0 = *(const float4*)(ea + (size_t)seA.y * 8);
    float4 a1 = *(const float4*)(ea + (size_t)seA.y * 8 + 4);
    float4 b0 = *(const float4*)(ea + (size_t)seB.y * 8);
    float4 b1 = *(const float4*)(ea + (size_t)seB.y * 8 + 4);
    float xaA[8] = {a0.x, a0.y, a0.z, a0.w, a1.x, a1.y, a1.z, a1.w};
    float xaB[8] = {b0.x, b0.y, b0.z, b0.w, b1.x, b1.y, b1.z, b1.w};
    floatx4 vA[16], vB[16];
    floatx4 sumA4 = {0.f, 0.f, 0.f, 0.f}, sumB4 = {0.f, 0.f, 0.f, 0.f};
    #pragma unroll
    for (int c4 = 0; c4 < 16; c4++) {
        floatx4 aa = sB4[c4], bb = aa;
        #pragma unroll
        for (int k = 0; k < 8; k++) {
            floatx4 w = sW4[k * 16 + c4];
            aa += xaA[k] * w;
            bb += xaB[k] * w;
        }
        vA[c4] = aa; sumA4 += aa;
        vB[c4] = bb; sumB4 += bb;
    }
    float mA = (sumA4[0] + sumA4[1] + sumA4[2] + sumA4[3]) * (1.f / 64.f);
    float mB = (sumB4[0] + sumB4[1] + sumB4[2] + sumB4[3]) * (1.f / 64.f);
    floatx4 varA4 = {0.f, 0.f, 0.f, 0.f}, varB4 = {0.f, 0.f, 0.f, 0.f};
    #pragma unroll
    for (int c4 = 0; c4 < 16; c4++) {
        floatx4 dA = vA[c4] - mA; varA4 += dA * dA;
        floatx4 dB = vB[c4] - mB; varB4 += dB * dB;
    }
    float rsA = rsqrtf((varA4[0] + varA4[1] + varA4[2] + varA4[3]) * (1.f / 64.f) + EPS);
    float rsB = rsqrtf((varB4[0] + varB4[1] + varB4[2] + varB4[3]) * (1.f / 64.f) + EPS);
    #pragma unroll
    for (int c4 = 0; c4 < 16; c4++) {
        floatx4 g = sG4[c4], be = sBe4[c4];
        floatx4 oA = (vA[c4] - mA) * rsA * g + be;
        floatx4 oB = (vB[c4] - mB) * rsB * g + be;
        #pragma unroll
        for (int p = 0; p < 4; p++) {
            vA[c4][p] = fmaxf(oA[p], 0.f);
            vB[c4][p] = fmaxf(oB[p], 0.f);
        }
    }
    floatx4 aE0A = {0.f,0.f,0.f,0.f}, aE1A = {0.f,0.f,0.f,0.f}, aE2A = {0.f,0.f,0.f,0.f};
    floatx4 aE0B = {0.f,0.f,0.f,0.f}, aE1B = {0.f,0.f,0.f,0.f}, aE2B = {0.f,0.f,0.f,0.f};
    #pragma unroll
    for (int c = 0; c < 64; c++) {
        float vcA = vA[c >> 2][c & 3];
        float vcB = vB[c >> 2][c & 3];
        floatx4 m0 = sM4[c * 3 + 0], m1 = sM4[c * 3 + 1], m2 = sM4[c * 3 + 2];
        aE0A += vcA * m0; aE1A += vcA * m1; aE2A += vcA * m2;
        aE0B += vcB * m0; aE1B += vcB * m1; aE2B += vcB * m2;
    }
    csr_src[s0] = seA.x;
    *(floatx4*)(csr_aE + ((size_t)0 * N_EDGES + s0) * 4) = aE0A;
    *(floatx4*)(csr_aE + ((size_t)1 * N_EDGES + s0) * 4) = aE1A;
    *(floatx4*)(csr_aE + ((size_t)2 * N_EDGES + s0) * 4) = aE2A;
    if (has1) {
        csr_src[s1] = seB.x;
        *(floatx4*)(csr_aE + ((size_t)0 * N_EDGES + s1) * 4) = aE0B;
        *(floatx4*)(csr_aE + ((size_t)1 * N_EDGES + s1) * 4) = aE1B;
        *(floatx4*)(csr_aE + ((size_t)2 * N_EDGES + s1) * 4) = aE2B;
    }
}

// ---- GEMM xs = h @ W via MFMA (3-term bf16 split), optional fused BN-apply ----
__global__ __launch_bounds__(256) void k_gemm_xs_mfma(
        float* __restrict__ h, const float* __restrict__ buf,
        const float* __restrict__ stats, const float* __restrict__ bng,
        const float* __restrict__ bnb, const u16* __restrict__ wt_hi,
        const u16* __restrict__ wt_lo, u16* __restrict__ xs, int fuse) {
    int wave = threadIdx.x >> 6, lane = threadIdx.x & 63;
    int r0 = (blockIdx.x * 4 + wave) * 16;
    if (r0 >= N_NODES) return;
    int lrow = lane & 15, lk = lane >> 4;
    size_t rowoff = (size_t)(r0 + lrow) * 128 + lk * 8;
    float* hp = h + rowoff;
    const float* bp = buf + rowoff;
    const u16* bph = wt_hi + lrow * 128 + lk * 8;
    const u16* bpl = wt_lo + lrow * 128 + lk * 8;
    floatx4 acc[8];
    #pragma unroll
    for (int j = 0; j < 8; j++) acc[j] = (floatx4){0.f, 0.f, 0.f, 0.f};
    #pragma unroll
    for (int s = 0; s < 4; s++) {
        float av[8];
        float4 h0 = *(const float4*)(hp + s * 32);
        float4 h1 = *(const float4*)(hp + s * 32 + 4);
        float hv[8] = {h0.x, h0.y, h0.z, h0.w, h1.x, h1.y, h1.z, h1.w};
        if (fuse) {
            float4 b0 = *(const float4*)(bp + s * 32);
            float4 b1 = *(const float4*)(bp + s * 32 + 4);
            float bv[8] = {b0.x, b0.y, b0.z, b0.w, b1.x, b1.y, b1.z, b1.w};
            #pragma unroll
            for (int i = 0; i < 8; i++) {
                int c = lk * 8 + s * 32 + i;
                float m = stats[c] * (1.f / N_NODES);
                float var = stats[128 + c] * (1.f / N_NODES) - m * m;
                float rsn = rsqrtf(var + EPS);
                float val = (bv[i] - m) * rsn * bng[c] + bnb[c] + hv[i];
                av[i] = fmaxf(val, 0.f);
            }
            float4 w0, w1;
            w0.x = av[0]; w0.y = av[1]; w0.z = av[2]; w0.w = av[3];
            w1.x = av[4]; w1.y = av[5]; w1.z = av[6]; w1.w = av[7];
            *(float4*)(hp + s * 32) = w0;
            *(float4*)(hp + s * 32 + 4) = w1;
        } else {
            #pragma unroll
            for (int i = 0; i < 8; i++) av[i] = hv[i];
        }
        short8_t ahi, alo;
        #pragma unroll
        for (int i = 0; i < 8; i++) {
            u16 hb = f2bf(av[i]);
            ahi[i] = (short)hb;
            alo[i] = (short)f2bf(av[i] - bf2f(hb));
        }
        short8_t bh[8], bl[8];
        #pragma unroll
        for (int j = 0; j < 8; j++) {
            bh[j] = *(const short8_t*)(bph + s * 32 + j * 2048);
            bl[j] = *(const short8_t*)(bpl + s * 32 + j * 2048);
        }
        #pragma unroll
        for (int j = 0; j < 8; j++)
            acc[j] = __builtin_amdgcn_mfma_f32_16x16x32_bf16(ahi, bh[j], acc[j], 0, 0, 0);
        #pragma unroll
        for (int j = 0; j < 8; j++)
            acc[j] = __builtin_amdgcn_mfma_f32_16x16x32_bf16(ahi, bl[j], acc[j], 0, 0, 0);
        #pragma unroll
        for (int j = 0; j < 8; j++)
            acc[j] = __builtin_amdgcn_mfma_f32_16x16x32_bf16(alo, bh[j], acc[j], 0, 0, 0);
    }
    // D: row = r0 + lk*4 + reg, col = j*16 + lrow
    u16* orow = xs + (size_t)(r0 + lk * 4) * 128 + lrow;
    #pragma unroll
    for (int j = 0; j < 8; j++) {
        #pragma unroll
        for (int reg = 0; reg < 4; reg++)
            orow[(size_t)reg * 128 + j * 16] = f2bf(acc[j][reg]);
    }
}

// ---- al_s / al_d per (node, head), vectorized xs loads ----
__global__ void k_al(const u16* __restrict__ xs, const float* __restrict__ as_,
                     const float* __restrict__ ad_, float* __restrict__ al_s,
                     float* __restrict__ al_d) {
    int t = blockIdx.x * 256 + threadIdx.x;
    if (t >= N_NODES * 4) return;
    int n = t >> 2, hh = t & 3;
    const uint4* xp = (const uint4*)(xs + (size_t)n * 128 + hh * 32);
    const float* app = as_ + hh * 32;
    const float* dpp = ad_ + hh * 32;
    float s = 0.f, d = 0.f;
    #pragma unroll
    for (int q = 0; q < 4; q++) {
        uint4 v = xp[q];
        u32 wv[4] = {v.x, v.y, v.z, v.w};
        #pragma unroll
        for (int p = 0; p < 4; p++) {
            int c = q * 8 + p * 2;
            float fl = lo_bf(wv[p]), fh = hi_bf(wv[p]);
            s = fmaf(fl, app[c], s); s = fmaf(fh, app[c + 1], s);
            d = fmaf(fl, dpp[c], d); d = fmaf(fh, dpp[c + 1], d);
        }
    }
    al_s[t] = s; al_d[t] = d;
}

// ---- GAT aggregation: wave per node, lane owns channel pair (2l, 2l+1) ----
__global__ __launch_bounds__(256) void k_agg(
        const int* __restrict__ rowptr, const int* __restrict__ csr_src,
        const float* __restrict__ aEl, const float* __restrict__ al_s,
        const float* __restrict__ al_d, const u16* __restrict__ xs,
        const float* __restrict__ bias, float* __restrict__ outp) {
    int lane = threadIdx.x & 63;
    int n = __builtin_amdgcn_readfirstlane(blockIdx.x * 4 + (threadIdx.x >> 6));
    if (n >= N_NODES) return;
    int row = rowptr[n], end = rowptr[n + 1];
    int hh = lane >> 4;
    const u32* xsw = (const u32*)xs;
    float ald = al_d[n * 4 + hh];
    float asn = al_s[n * 4 + hh];
    u32 xnp = xsw[(size_t)n * 64 + lane];
    float acc0 = 0.f, acc1 = 0.f, ssum = 0.f, aes = 0.f;
    int slot = row;
    for (; slot + 8 <= end; slot += 8) {
        int sv[8]; float ae[8], asv[8]; u32 xv[8];
        #pragma unroll
        for (int i = 0; i < 8; i++) sv[i] = csr_src[slot + i];
        #pragma unroll
        for (int i = 0; i < 8; i++) ae[i] = aEl[(size_t)(slot + i) * 4 + hh];
        #pragma unroll
        for (int i = 0; i < 8; i++) asv[i] = al_s[sv[i] * 4 + hh];
        #pragma unroll
        for (int i = 0; i < 8; i++) xv[i] = xsw[(size_t)sv[i] * 64 + lane];
        #pragma unroll
        for (int i = 0; i < 8; i++) {
            aes += ae[i];
            float a = asv[i] + ald + ae[i]; a = (a >= 0.f) ? a : SLOPE * a;
            float ev = __expf(a);
            ssum += ev;
            acc0 = fmaf(ev, lo_bf(xv[i]), acc0);
            acc1 = fmaf(ev, hi_bf(xv[i]), acc1);
        }
    }
    for (; slot + 4 <= end; slot += 4) {
        int sv[4]; float ae[4], asv[4]; u32 xv[4];
        #pragma unroll
        for (int i = 0; i < 4; i++) sv[i] = csr_src[slot + i];
        #pragma unroll
        for (int i = 0; i < 4; i++) ae[i] = aEl[(size_t)(slot + i) * 4 + hh];
        #pragma unroll
        for (int i = 0; i < 4; i++) asv[i] = al_s[sv[i] * 4 + hh];
        #pragma unroll
        for (int i = 0; i < 4; i++) xv[i] = xsw[(size_t)sv[i] * 64 + lane];
        #pragma unroll
        for (int i = 0; i < 4; i++) {
            aes += ae[i];
            float a = asv[i] + ald + ae[i]; a = (a >= 0.f) ? a : SLOPE * a;
            float ev = __expf(a);
            ssum += ev;
            acc0 = fmaf(ev, lo_bf(xv[i]), acc0);
            acc1 = fmaf(ev, hi_bf(xv[i]), acc1);
        }
    }
    for (; slot < end; slot++) {
        int sA = csr_src[slot];
        float aeA = aEl[(size_t)slot * 4 + hh];
        float asA = al_s[sA * 4 + hh];
        u32 xA = xsw[(size_t)sA * 64 + lane];
        aes += aeA;
        float aA = asA + ald + aeA; aA = (aA >= 0.f) ? aA : SLOPE * aA;
        float eA = __expf(aA);
        ssum += eA;
        acc0 = fmaf(eA, lo_bf(xA), acc0); acc1 = fmaf(eA, hi_bf(xA), acc1);
    }
    // self-loop (PyG add_self_loops, fill_value='mean'): aE = mean over row
    float dinv = 1.f / fmaxf((float)(end - row), 1.f);
    float sa = asn + ald + aes * dinv; sa = (sa >= 0.f) ? sa : SLOPE * sa;
    float e = __expf(sa);
    ssum += e;
    acc0 = fmaf(e, lo_bf(xnp), acc0); acc1 = fmaf(e, hi_bf(xnp), acc1);
    float2 bv = *(const float2*)(bias + lane * 2);
    float2 o;
    o.x = acc0 / ssum + bv.x;
    o.y = acc1 / ssum + bv.y;
    *(float2*)(outp + (size_t)n * 128 + lane * 2) = o;
}

// ---- BN stats (sum, sumsq per channel) ----
__global__ void k_bn_stats(const float* __restrict__ x, float* __restrict__ stats) {
    __shared__ float lds[512];
    int t = threadIdx.x;
    int c = t & 127, half = t >> 7;
    float s = 0.f, q = 0.f;
    for (int n = blockIdx.x * 2 + half; n < N_NODES; n += gridDim.x * 2) {
        float v = x[(size_t)n * 128 + c];
        s += v; q = fmaf(v, v, q);
    }
    lds[t] = s; lds[256 + t] = q;
    __syncthreads();
    if (t < 128) {
        atomicAdd(&stats[c], lds[t] + lds[t + 128]);
        atomicAdd(&stats[128 + c], lds[256 + t] + lds[256 + t + 128]);
    }
}

// ---- final proj: fused BN-apply + MFMA GEMM (3-term bf16 split) + bias + LN ----
__global__ __launch_bounds__(256) void k_gemm_fp_mfma(
        const float* __restrict__ h, const float* __restrict__ buf,
        const float* __restrict__ stats, const float* __restrict__ bng,
        const float* __restrict__ bnb, const u16* __restrict__ wt_hi,
        const u16* __restrict__ wt_lo, const float* __restrict__ fb,
        const float* __restrict__ g, const float* __restrict__ be,
        float* __restrict__ out) {
    int wave = threadIdx.x >> 6, lane = threadIdx.x & 63;
    int r0 = (blockIdx.x * 4 + wave) * 16;
    if (r0 >= N_NODES) return;
    int lrow = lane & 15, lk = lane >> 4;
    size_t rowoff = (size_t)(r0 + lrow) * 128 + lk * 8;
    const float* hp = h + rowoff;
    const float* bp = buf + rowoff;
    const u16* bph = wt_hi + lrow * 128 + lk * 8;
    const u16* bpl = wt_lo + lrow * 128 + lk * 8;
    floatx4 acc[8];
    #pragma unroll
    for (int j = 0; j < 8; j++) acc[j] = (floatx4){0.f, 0.f, 0.f, 0.f};
    #pragma unroll
    for (int s = 0; s < 4; s++) {
        float4 h0 = *(const float4*)(hp + s * 32);
        float4 h1 = *(const float4*)(hp + s * 32 + 4);
        float4 b0 = *(const float4*)(bp + s * 32);
        float4 b1 = *(const float4*)(bp + s * 32 + 4);
        float hv[8] = {h0.x, h0.y, h0.z, h0.w, h1.x, h1.y, h1.z, h1.w};
        float bvv[8] = {b0.x, b0.y, b0.z, b0.w, b1.x, b1.y, b1.z, b1.w};
        float av[8];
        #pragma unroll
        for (int i = 0; i < 8; i++) {
            int c = lk * 8 + s * 32 + i;
            float m = stats[c] * (1.f / N_NODES);
            float var = stats[128 + c] * (1.f / N_NODES) - m * m;
            float rsn = rsqrtf(var + EPS);
            float val = (bvv[i] - m) * rsn * bng[c] + bnb[c] + hv[i];
            av[i] = fmaxf(val, 0.f);
        }
        short8_t ahi, alo;
        #pragma unroll
        for (int i = 0; i < 8; i++) {
            u16 hb = f2bf(av[i]);
            ahi[i] = (short)hb;
            alo[i] = (short)f2bf(av[i] - bf2f(hb));
        }
        short8_t bh[8], bl[8];
        #pragma unroll
        for (int j = 0; j < 8; j++) {
            bh[j] = *(const short8_t*)(bph + s * 32 + j * 2048);
            bl[j] = *(const short8_t*)(bpl + s * 32 + j * 2048);
        }
        #pragma unroll
        for (int j = 0; j < 8; j++)
            acc[j] = __builtin_amdgcn_mfma_f32_16x16x32_bf16(ahi, bh[j], acc[j], 0, 0, 0);
        #pragma unroll
        for (int j = 0; j < 8; j++)
            acc[j] = __builtin_amdgcn_mfma_f32_16x16x32_bf16(ahi, bl[j], acc[j], 0, 0, 0);
        #pragma unroll
        for (int j = 0; j < 8; j++)
            acc[j] = __builtin_amdgcn_mfma_f32_16x16x32_bf16(alo, bh[j], acc[j], 0, 0, 0);
    }
    // epilogue: y = acc + fb ; LN over each row (r0 + lk*4 + reg)
    float gv[8], bev[8];
    #pragma unroll
    for (int j = 0; j < 8; j++) {
        float fbv = fb[j * 16 + lrow];
        gv[j] = g[j * 16 + lrow];
        bev[j] = be[j * 16 + lrow];
        #pragma unroll
        for (int reg = 0; reg < 4; reg++) acc[j][reg] += fbv;
    }
    float s1[4] = {0.f, 0.f, 0.f, 0.f}, s2[4] = {0.f, 0.f, 0.f, 0.f};
    #pragma unroll
    for (int j = 0; j < 8; j++) {
        #pragma unroll
        for (int reg = 0; reg < 4; reg++) {
            float y = acc[j][reg];
            s1[reg] += y;
            s2[reg] = fmaf(y, y, s2[reg]);
        }
    }
    #pragma unroll
    for (int off = 1; off <= 8; off <<= 1) {
        #pragma unroll
        for (int reg = 0; reg < 4; reg++) {
            s1[reg] += __shfl_xor(s1[reg], off, 64);
            s2[reg] += __shfl_xor(s2[reg], off, 64);
        }
    }
    #pragma unroll
    for (int reg = 0; reg < 4; reg++) {
        float m = s1[reg] * (1.f / 128.f);
        float var = s2[reg] * (1.f / 128.f) - m * m;
        float rs = rsqrtf(var + EPS);
        float* orow = out + (size_t)(r0 + lk * 4 + reg) * 128 + lrow;
        #pragma unroll
        for (int j = 0; j < 8; j++)
            orow[j * 16] = (acc[j][reg] - m) * rs * gv[j] + bev[j];
    }
}

extern "C" void kernel_launch(void* const* d_in, const int* in_sizes, int n_in,
                              void* d_out, int out_size, void* d_ws, size_t ws_size,
                              hipStream_t stream) {
    const float* x      = (const float*)d_in[0];
    const int*   ei     = (const int*)d_in[1];
    const float* ea     = (const float*)d_in[2];
    const float* np_w   = (const float*)d_in[3];
    const float* np_b   = (const float*)d_in[4];
    const float* np_g   = (const float*)d_in[5];
    const float* np_be  = (const float*)d_in[6];
    const float* ep_w   = (const float*)d_in[7];
    const float* ep_b   = (const float*)d_in[8];
    const float* ep_g   = (const float*)d_in[9];
    const float* ep_be  = (const float*)d_in[10];
    const float* gat_w  = (const float*)d_in[11];
    const float* gat_as = (const float*)d_in[12];
    const float* gat_ad = (const float*)d_in[13];
    const float* gat_ew = (const float*)d_in[14];
    const float* gat_ae = (const float*)d_in[15];
    const float* gat_b  = (const float*)d_in[16];
    const float* bn_g   = (const float*)d_in[17];
    const float* bn_b   = (const float*)d_in[18];
    const float* fp_w   = (const float*)d_in[19];
    const float* fp_b   = (const float*)d_in[20];
    const float* fp_g   = (const float*)d_in[21];
    const float* fp_be  = (const float*)d_in[22];
    float* out = (float*)d_out;

    char* ws = (char*)d_ws;
    size_t off = 0;
    auto alloc = [&](size_t bytes) -> void* {
        void* p = ws + off;
        off = (off + bytes + 255) & ~(size_t)255;
        return p;
    };
    // Workspace layout IDENTICAL to the passing round-9 kernel (no growth).
    float* h      = (float*)alloc((size_t)N_NODES * 128 * 4);
    float* buf    = (float*)alloc((size_t)N_NODES * 128 * 4);
    u16*   xs     = (u16*)alloc((size_t)N_NODES * 128 * 2);
    float* al_s   = (float*)alloc((size_t)N_NODES * 4 * 4);
    float* al_d   = (float*)alloc((size_t)N_NODES * 4 * 4);
    int*   deg    = (int*)alloc((size_t)N_NODES * 4);
    int*   rowptr = (int*)alloc((size_t)(N_NODES + 1) * 4);
    int*   cursor = (int*)alloc((size_t)N_NODES * 4);
    int*   incl   = (int*)alloc((size_t)N_NODES * 4);
    int*   bsum   = (int*)alloc(64 * 4);
    int*   csr_src= (int*)alloc((size_t)N_EDGES * 4);
    float* csr_aE = (float*)alloc((size_t)N_EDGES * 12 * 4);   // SoA [3][E][4]
    float* M      = (float*)alloc(64 * 12 * 4);
    float* stats  = (float*)alloc(256 * 4);
    u16*   wt_hi  = (u16*)alloc((size_t)3 * 16384 * 2);
    u16*   wt_lo  = (u16*)alloc((size_t)3 * 16384 * 2);
    (void)cursor;
    // csr_se aliases buf: buf is first written by k_agg (layer 0), strictly
    // after k_edge_c's last read of csr_se on the same stream.
    int2*  csr_se = (int2*)buf;
    // rank aliases xs: rank written by k_deg, read by k_fill; xs first written
    // by k_gemm_xs_mfma (layer 0), strictly after k_fill.
    int*   rank   = (int*)xs;
    // fp-proj split weights alias incl (scan scratch, dead after k_scan3).
    u16*   wtf_hi = (u16*)incl;
    u16*   wtf_lo = wtf_hi + 16384;

    hipMemsetAsync(deg, 0, (size_t)N_NODES * 4, stream);

    k_M<<<1, 768, 0, stream>>>(gat_ew, gat_ae, M);
    k_convW<<<192, 256, 0, stream>>>(gat_w, wt_hi, wt_lo, 3 * 16384);
    k_node_pre<<<(N_NODES + 3) / 4, 256, 0, stream>>>(x, np_w, np_b, np_g, np_be, h);
    k_deg<<<(N_EDGES + 255) / 256, 256, 0, stream>>>(ei + N_EDGES, deg, rank);
    int nblk = (N_NODES + 1023) / 1024;
    k_scan1<<<nblk, 1024, 0, stream>>>(deg, incl, bsum);
    k_scan2<<<1, 64, 0, stream>>>(bsum, nblk);
    k_scan3<<<nblk, 1024, 0, stream>>>(incl, bsum, rowptr);
    // incl is dead from here on; convert fp_w into its space.
    k_convW<<<64, 256, 0, stream>>>(fp_w, wtf_hi, wtf_lo, 16384);
    k_fill<<<(N_EDGES + 255) / 256, 256, 0, stream>>>(ei, rowptr, rank, csr_se);
    k_edge_c<<<(N_EDGES + 511) / 512, 256, 0, stream>>>(csr_se, ea, ep_w, ep_b, ep_g,
                                                        ep_be, M, csr_src, csr_aE);

    for (int l = 0; l < 3; l++) {
        // l>0: fuse previous layer's BN-apply (stats of layer l-1) into A-load.
        k_gemm_xs_mfma<<<(3125 + 3) / 4, 256, 0, stream>>>(
            h, buf, stats, bn_g + (l > 0 ? (l - 1) * 128 : 0),
            bn_b + (l > 0 ? (l - 1) * 128 : 0),
            wt_hi + (size_t)l * 16384, wt_lo + (size_t)l * 16384, xs, l > 0 ? 1 : 0);
        k_al<<<(N_NODES * 4 + 255) / 256, 256, 0, stream>>>(xs, gat_as + l * 128,
                                                            gat_ad + l * 128, al_s, al_d);
        hipMemsetAsync(stats, 0, 256 * 4, stream);
        k_agg<<<(N_NODES + 3) / 4, 256, 0, stream>>>(rowptr, csr_src,
                                                     csr_aE + (size_t)l * N_EDGES * 4,
                                                     al_s, al_d, xs, gat_b + l * 128, buf);
        k_bn_stats<<<256, 256, 0, stream>>>(buf, stats);
    }
    // final: fuse layer-2 BN-apply into the fp GEMM A-load.
    k_gemm_fp_mfma<<<(3125 + 3) / 4, 256, 0, stream>>>(
        h, buf, stats, bn_g + 2 * 128, bn_b + 2 * 128,
        wtf_hi, wtf_lo, fp_b, fp_g, fp_be, out);
}

// Round 11
// 673.101 us; speedup vs baseline: 1.4895x; 1.4895x over previous
//
#include <hip/hip_runtime.h>
#include <hip/hip_bf16.h>
#include <math.h>

#define N_NODES 50000
#define N_EDGES 800000
#define EPS 1e-5f
#define SLOPE 0.2f

typedef unsigned int u32;
typedef unsigned short u16;
typedef float floatx4 __attribute__((ext_vector_type(4)));
typedef short short8_t __attribute__((ext_vector_type(8)));

__device__ __forceinline__ float bf2f(u16 v) {
    u32 u = ((u32)v) << 16;
    return __uint_as_float(u);
}
__device__ __forceinline__ u16 f2bf(float f) {
    u32 u = __float_as_uint(f);
    u32 r = (u + 0x7fffu + ((u >> 16) & 1u)) >> 16;  // RNE
    return (u16)r;
}
__device__ __forceinline__ float lo_bf(u32 v) { return __uint_as_float(v << 16); }
__device__ __forceinline__ float hi_bf(u32 v) { return __uint_as_float(v & 0xffff0000u); }
__device__ __forceinline__ float wred(float v) {
    #pragma unroll
    for (int off = 32; off > 0; off >>= 1) v += __shfl_xor(v, off, 64);
    return v;
}

// ---- M[k][l*4+h] = sum_c gat_ew[l][k][h*32+c] * gat_ae[l][h][c] ----
__global__ void k_M(const float* __restrict__ ew, const float* __restrict__ ae,
                    float* __restrict__ M) {
    int t = threadIdx.x;
    if (t >= 768) return;
    int k = t / 12, j = t % 12;
    int l = j >> 2, h = j & 3;
    const float* ewp = ew + l * 8192 + k * 128 + h * 32;
    const float* aep = ae + l * 128 + h * 32;
    float s = 0.f;
    #pragma unroll
    for (int c = 0; c < 32; c++) s += ewp[c] * aep[c];
    M[k * 12 + j] = s;
}

// ---- split-transpose 128x128 fp32 weights: wt[l][n][k] = bf16split(w[l][k][n]) ----
__global__ void k_convW(const float* __restrict__ w, u16* __restrict__ hi,
                        u16* __restrict__ lo, int total) {
    int i = blockIdx.x * 256 + threadIdx.x;
    if (i >= total) return;
    int l = i >> 14, r = i & 16383;
    int n = r >> 7, k = r & 127;
    float f = w[(size_t)l * 16384 + k * 128 + n];
    u16 hb = f2bf(f);
    hi[i] = hb;
    lo[i] = f2bf(f - bf2f(hb));
}

// ---- node preprocess: h = relu(LN(x @ np_w + np_b)) ; wave per node ----
__global__ __launch_bounds__(256) void k_node_pre(
        const float* __restrict__ x, const float* __restrict__ w,
        const float* __restrict__ b, const float* __restrict__ g,
        const float* __restrict__ be, float* __restrict__ h) {
    int wave = threadIdx.x >> 6, lane = threadIdx.x & 63;
    int n = blockIdx.x * 4 + wave;
    if (n >= N_NODES) return;
    const float* xr = x + (size_t)n * 16;
    float xv[16];
    #pragma unroll
    for (int k = 0; k < 16; k++) xv[k] = xr[k];
    int c0 = lane, c1 = lane + 64;
    float a0 = b[c0], a1 = b[c1];
    #pragma unroll
    for (int k = 0; k < 16; k++) {
        a0 = fmaf(xv[k], w[k * 128 + c0], a0);
        a1 = fmaf(xv[k], w[k * 128 + c1], a1);
    }
    float m = wred(a0 + a1) * (1.f / 128.f);
    float d0 = a0 - m, d1 = a1 - m;
    float v = wred(d0 * d0 + d1 * d1) * (1.f / 128.f);
    float rs = rsqrtf(v + EPS);
    float o0 = d0 * rs * g[c0] + be[c0];
    float o1 = d1 * rs * g[c1] + be[c1];
    h[(size_t)n * 128 + c0] = fmaxf(o0, 0.f);
    h[(size_t)n * 128 + c1] = fmaxf(o1, 0.f);
}

// ---- degree count + within-row rank (atomic return value, coalesced write) ----
__global__ void k_deg(const int* __restrict__ dst, int* __restrict__ deg,
                      int* __restrict__ rank) {
    int e = blockIdx.x * 256 + threadIdx.x;
    if (e < N_EDGES) rank[e] = atomicAdd(&deg[dst[e]], 1);
}

// ---- 3-phase exclusive scan -> rowptr ----
__global__ void k_scan1(const int* __restrict__ deg, int* __restrict__ incl,
                        int* __restrict__ bsum) {
    __shared__ int lds[1024];
    int i = blockIdx.x * 1024 + threadIdx.x;
    int v = (i < N_NODES) ? deg[i] : 0;
    lds[threadIdx.x] = v;
    __syncthreads();
    for (int off = 1; off < 1024; off <<= 1) {
        int t = (threadIdx.x >= off) ? lds[threadIdx.x - off] : 0;
        __syncthreads();
        lds[threadIdx.x] += t;
        __syncthreads();
    }
    if (i < N_NODES) incl[i] = lds[threadIdx.x];
    if (threadIdx.x == 1023) bsum[blockIdx.x] = lds[1023];
}
__global__ void k_scan2(int* __restrict__ bsum, int nb) {
    if (threadIdx.x == 0 && blockIdx.x == 0) {
        int run = 0;
        for (int i = 0; i < nb; i++) { int t = bsum[i]; bsum[i] = run; run += t; }
    }
}
__global__ void k_scan3(const int* __restrict__ incl, const int* __restrict__ bsum,
                        int* __restrict__ rowptr) {
    int i = blockIdx.x * 1024 + threadIdx.x;
    if (i < N_NODES) rowptr[i + 1] = incl[i] + bsum[blockIdx.x];
    if (i == 0) rowptr[0] = 0;
}

// ---- CSR slot fill: atomic-free scatter (slot = rowptr[dst] + rank[e]) ----
__global__ void k_fill(const int* __restrict__ ei, const int* __restrict__ rowptr,
                       const int* __restrict__ rank, int2* __restrict__ csr_se) {
    int e = blockIdx.x * 256 + threadIdx.x;
    if (e >= N_EDGES) return;
    int src = ei[e], dst = ei[N_EDGES + e];
    int slot = rowptr[dst] + rank[e];
    csr_se[slot] = make_int2(src, e);
}

// ---- edge preprocess + alphaE over SLOTS: 1 edge/thread, float4-packed ----
__global__ __launch_bounds__(256) void k_edge_c(
        const int2* __restrict__ csr_se, const float* __restrict__ ea,
        const float* __restrict__ epw, const float* __restrict__ epb,
        const float* __restrict__ epg, const float* __restrict__ epbe,
        const float* __restrict__ M, int* __restrict__ csr_src,
        float* __restrict__ csr_aE) {
    __shared__ floatx4 sW4[128], sM4[192], sB4[16], sG4[16], sBe4[16];
    int tid = threadIdx.x;
    if (tid < 128) sW4[tid] = ((const floatx4*)epw)[tid];
    if (tid < 192) sM4[tid] = ((const floatx4*)M)[tid];
    if (tid < 16) sB4[tid] = ((const floatx4*)epb)[tid];
    if (tid >= 32 && tid < 48) sG4[tid - 32] = ((const floatx4*)epg)[tid - 32];
    if (tid >= 64 && tid < 80) sBe4[tid - 64] = ((const floatx4*)epbe)[tid - 64];
    __syncthreads();
    int s = blockIdx.x * 256 + tid;
    if (s >= N_EDGES) return;
    int2 se = csr_se[s];
    int src = se.x, e = se.y;
    float4 x0 = *(const float4*)(ea + (size_t)e * 8);
    float4 x1 = *(const float4*)(ea + (size_t)e * 8 + 4);
    float xa[8] = {x0.x, x0.y, x0.z, x0.w, x1.x, x1.y, x1.z, x1.w};
    floatx4 v4[16];
    floatx4 sum4 = {0.f, 0.f, 0.f, 0.f};
    #pragma unroll
    for (int c4 = 0; c4 < 16; c4++) {
        floatx4 a = sB4[c4];
        #pragma unroll
        for (int k = 0; k < 8; k++) a += xa[k] * sW4[k * 16 + c4];
        v4[c4] = a;
        sum4 += a;
    }
    float m = (sum4[0] + sum4[1] + sum4[2] + sum4[3]) * (1.f / 64.f);
    floatx4 var4 = {0.f, 0.f, 0.f, 0.f};
    #pragma unroll
    for (int c4 = 0; c4 < 16; c4++) { floatx4 d = v4[c4] - m; var4 += d * d; }
    float rs = rsqrtf((var4[0] + var4[1] + var4[2] + var4[3]) * (1.f / 64.f) + EPS);
    #pragma unroll
    for (int c4 = 0; c4 < 16; c4++) {
        floatx4 o = (v4[c4] - m) * rs * sG4[c4] + sBe4[c4];
        #pragma unroll
        for (int p = 0; p < 4; p++) v4[c4][p] = fmaxf(o[p], 0.f);
    }
    floatx4 aE0 = {0.f, 0.f, 0.f, 0.f};
    floatx4 aE1 = {0.f, 0.f, 0.f, 0.f};
    floatx4 aE2 = {0.f, 0.f, 0.f, 0.f};
    #pragma unroll
    for (int c = 0; c < 64; c++) {
        float vc = v4[c >> 2][c & 3];
        aE0 += vc * sM4[c * 3 + 0];
        aE1 += vc * sM4[c * 3 + 1];
        aE2 += vc * sM4[c * 3 + 2];
    }
    csr_src[s] = src;
    *(floatx4*)(csr_aE + ((size_t)0 * N_EDGES + s) * 4) = aE0;
    *(floatx4*)(csr_aE + ((size_t)1 * N_EDGES + s) * 4) = aE1;
    *(floatx4*)(csr_aE + ((size_t)2 * N_EDGES + s) * 4) = aE2;
}

// ---- GEMM xs = h @ W via MFMA (3-term bf16 split), optional fused BN-apply ----
__global__ __launch_bounds__(256) void k_gemm_xs_mfma(
        float* __restrict__ h, const float* __restrict__ buf,
        const float* __restrict__ stats, const float* __restrict__ bng,
        const float* __restrict__ bnb, const u16* __restrict__ wt_hi,
        const u16* __restrict__ wt_lo, u16* __restrict__ xs, int fuse) {
    int wave = threadIdx.x >> 6, lane = threadIdx.x & 63;
    int r0 = (blockIdx.x * 4 + wave) * 16;
    if (r0 >= N_NODES) return;
    int lrow = lane & 15, lk = lane >> 4;
    size_t rowoff = (size_t)(r0 + lrow) * 128 + lk * 8;
    float* hp = h + rowoff;
    const float* bp = buf + rowoff;
    const u16* bph = wt_hi + lrow * 128 + lk * 8;
    const u16* bpl = wt_lo + lrow * 128 + lk * 8;
    floatx4 acc[8];
    #pragma unroll
    for (int j = 0; j < 8; j++) acc[j] = (floatx4){0.f, 0.f, 0.f, 0.f};
    #pragma unroll
    for (int s = 0; s < 4; s++) {
        float av[8];
        float4 h0 = *(const float4*)(hp + s * 32);
        float4 h1 = *(const float4*)(hp + s * 32 + 4);
        float hv[8] = {h0.x, h0.y, h0.z, h0.w, h1.x, h1.y, h1.z, h1.w};
        if (fuse) {
            float4 b0 = *(const float4*)(bp + s * 32);
            float4 b1 = *(const float4*)(bp + s * 32 + 4);
            float bv[8] = {b0.x, b0.y, b0.z, b0.w, b1.x, b1.y, b1.z, b1.w};
            #pragma unroll
            for (int i = 0; i < 8; i++) {
                int c = lk * 8 + s * 32 + i;
                float m = stats[c] * (1.f / N_NODES);
                float var = stats[128 + c] * (1.f / N_NODES) - m * m;
                float rsn = rsqrtf(var + EPS);
                float val = (bv[i] - m) * rsn * bng[c] + bnb[c] + hv[i];
                av[i] = fmaxf(val, 0.f);
            }
            float4 w0, w1;
            w0.x = av[0]; w0.y = av[1]; w0.z = av[2]; w0.w = av[3];
            w1.x = av[4]; w1.y = av[5]; w1.z = av[6]; w1.w = av[7];
            *(float4*)(hp + s * 32) = w0;
            *(float4*)(hp + s * 32 + 4) = w1;
        } else {
            #pragma unroll
            for (int i = 0; i < 8; i++) av[i] = hv[i];
        }
        short8_t ahi, alo;
        #pragma unroll
        for (int i = 0; i < 8; i++) {
            u16 hb = f2bf(av[i]);
            ahi[i] = (short)hb;
            alo[i] = (short)f2bf(av[i] - bf2f(hb));
        }
        short8_t bh[8], bl[8];
        #pragma unroll
        for (int j = 0; j < 8; j++) {
            bh[j] = *(const short8_t*)(bph + s * 32 + j * 2048);
            bl[j] = *(const short8_t*)(bpl + s * 32 + j * 2048);
        }
        #pragma unroll
        for (int j = 0; j < 8; j++)
            acc[j] = __builtin_amdgcn_mfma_f32_16x16x32_bf16(ahi, bh[j], acc[j], 0, 0, 0);
        #pragma unroll
        for (int j = 0; j < 8; j++)
            acc[j] = __builtin_amdgcn_mfma_f32_16x16x32_bf16(ahi, bl[j], acc[j], 0, 0, 0);
        #pragma unroll
        for (int j = 0; j < 8; j++)
            acc[j] = __builtin_amdgcn_mfma_f32_16x16x32_bf16(alo, bh[j], acc[j], 0, 0, 0);
    }
    // D: row = r0 + lk*4 + reg, col = j*16 + lrow
    u16* orow = xs + (size_t)(r0 + lk * 4) * 128 + lrow;
    #pragma unroll
    for (int j = 0; j < 8; j++) {
        #pragma unroll
        for (int reg = 0; reg < 4; reg++)
            orow[(size_t)reg * 128 + j * 16] = f2bf(acc[j][reg]);
    }
}

// ---- al_s / al_d per (node, head), vectorized xs loads ----
__global__ void k_al(const u16* __restrict__ xs, const float* __restrict__ as_,
                     const float* __restrict__ ad_, float* __restrict__ al_s,
                     float* __restrict__ al_d) {
    int t = blockIdx.x * 256 + threadIdx.x;
    if (t >= N_NODES * 4) return;
    int n = t >> 2, hh = t & 3;
    const uint4* xp = (const uint4*)(xs + (size_t)n * 128 + hh * 32);
    const float* app = as_ + hh * 32;
    const float* dpp = ad_ + hh * 32;
    float s = 0.f, d = 0.f;
    #pragma unroll
    for (int q = 0; q < 4; q++) {
        uint4 v = xp[q];
        u32 wv[4] = {v.x, v.y, v.z, v.w};
        #pragma unroll
        for (int p = 0; p < 4; p++) {
            int c = q * 8 + p * 2;
            float fl = lo_bf(wv[p]), fh = hi_bf(wv[p]);
            s = fmaf(fl, app[c], s); s = fmaf(fh, app[c + 1], s);
            d = fmaf(fl, dpp[c], d); d = fmaf(fh, dpp[c + 1], d);
        }
    }
    al_s[t] = s; al_d[t] = d;
}

// ---- GAT aggregation: wave per node, lane owns channel pair (2l, 2l+1) ----
__global__ __launch_bounds__(256) void k_agg(
        const int* __restrict__ rowptr, const int* __restrict__ csr_src,
        const float* __restrict__ aEl, const float* __restrict__ al_s,
        const float* __restrict__ al_d, const u16* __restrict__ xs,
        const float* __restrict__ bias, float* __restrict__ outp) {
    int lane = threadIdx.x & 63;
    int n = __builtin_amdgcn_readfirstlane(blockIdx.x * 4 + (threadIdx.x >> 6));
    if (n >= N_NODES) return;
    int row = rowptr[n], end = rowptr[n + 1];
    int hh = lane >> 4;
    const u32* xsw = (const u32*)xs;
    float ald = al_d[n * 4 + hh];
    float asn = al_s[n * 4 + hh];
    u32 xnp = xsw[(size_t)n * 64 + lane];
    float acc0 = 0.f, acc1 = 0.f, ssum = 0.f, aes = 0.f;
    int slot = row;
    for (; slot + 8 <= end; slot += 8) {
        int sv[8]; float ae[8], asv[8]; u32 xv[8];
        #pragma unroll
        for (int i = 0; i < 8; i++) sv[i] = csr_src[slot + i];
        #pragma unroll
        for (int i = 0; i < 8; i++) ae[i] = aEl[(size_t)(slot + i) * 4 + hh];
        #pragma unroll
        for (int i = 0; i < 8; i++) asv[i] = al_s[sv[i] * 4 + hh];
        #pragma unroll
        for (int i = 0; i < 8; i++) xv[i] = xsw[(size_t)sv[i] * 64 + lane];
        #pragma unroll
        for (int i = 0; i < 8; i++) {
            aes += ae[i];
            float a = asv[i] + ald + ae[i]; a = (a >= 0.f) ? a : SLOPE * a;
            float ev = __expf(a);
            ssum += ev;
            acc0 = fmaf(ev, lo_bf(xv[i]), acc0);
            acc1 = fmaf(ev, hi_bf(xv[i]), acc1);
        }
    }
    for (; slot + 4 <= end; slot += 4) {
        int sv[4]; float ae[4], asv[4]; u32 xv[4];
        #pragma unroll
        for (int i = 0; i < 4; i++) sv[i] = csr_src[slot + i];
        #pragma unroll
        for (int i = 0; i < 4; i++) ae[i] = aEl[(size_t)(slot + i) * 4 + hh];
        #pragma unroll
        for (int i = 0; i < 4; i++) asv[i] = al_s[sv[i] * 4 + hh];
        #pragma unroll
        for (int i = 0; i < 4; i++) xv[i] = xsw[(size_t)sv[i] * 64 + lane];
        #pragma unroll
        for (int i = 0; i < 4; i++) {
            aes += ae[i];
            float a = asv[i] + ald + ae[i]; a = (a >= 0.f) ? a : SLOPE * a;
            float ev = __expf(a);
            ssum += ev;
            acc0 = fmaf(ev, lo_bf(xv[i]), acc0);
            acc1 = fmaf(ev, hi_bf(xv[i]), acc1);
        }
    }
    for (; slot < end; slot++) {
        int sA = csr_src[slot];
        float aeA = aEl[(size_t)slot * 4 + hh];
        float asA = al_s[sA * 4 + hh];
        u32 xA = xsw[(size_t)sA * 64 + lane];
        aes += aeA;
        float aA = asA + ald + aeA; aA = (aA >= 0.f) ? aA : SLOPE * aA;
        float eA = __expf(aA);
        ssum += eA;
        acc0 = fmaf(eA, lo_bf(xA), acc0); acc1 = fmaf(eA, hi_bf(xA), acc1);
    }
    // self-loop (PyG add_self_loops, fill_value='mean'): aE = mean over row
    float dinv = 1.f / fmaxf((float)(end - row), 1.f);
    float sa = asn + ald + aes * dinv; sa = (sa >= 0.f) ? sa : SLOPE * sa;
    float e = __expf(sa);
    ssum += e;
    acc0 = fmaf(e, lo_bf(xnp), acc0); acc1 = fmaf(e, hi_bf(xnp), acc1);
    float2 bv = *(const float2*)(bias + lane * 2);
    float2 o;
    o.x = acc0 / ssum + bv.x;
    o.y = acc1 / ssum + bv.y;
    *(float2*)(outp + (size_t)n * 128 + lane * 2) = o;
}

// ---- BN stats (sum, sumsq per channel) ----
__global__ void k_bn_stats(const float* __restrict__ x, float* __restrict__ stats) {
    __shared__ float lds[512];
    int t = threadIdx.x;
    int c = t & 127, half = t >> 7;
    float s = 0.f, q = 0.f;
    for (int n = blockIdx.x * 2 + half; n < N_NODES; n += gridDim.x * 2) {
        float v = x[(size_t)n * 128 + c];
        s += v; q = fmaf(v, v, q);
    }
    lds[t] = s; lds[256 + t] = q;
    __syncthreads();
    if (t < 128) {
        atomicAdd(&stats[c], lds[t] + lds[t + 128]);
        atomicAdd(&stats[128 + c], lds[256 + t] + lds[256 + t + 128]);
    }
}

// ---- final proj: fused BN-apply + MFMA GEMM (3-term bf16 split) + bias + LN ----
__global__ __launch_bounds__(256) void k_gemm_fp_mfma(
        const float* __restrict__ h, const float* __restrict__ buf,
        const float* __restrict__ stats, const float* __restrict__ bng,
        const float* __restrict__ bnb, const u16* __restrict__ wt_hi,
        const u16* __restrict__ wt_lo, const float* __restrict__ fb,
        const float* __restrict__ g, const float* __restrict__ be,
        float* __restrict__ out) {
    int wave = threadIdx.x >> 6, lane = threadIdx.x & 63;
    int r0 = (blockIdx.x * 4 + wave) * 16;
    if (r0 >= N_NODES) return;
    int lrow = lane & 15, lk = lane >> 4;
    size_t rowoff = (size_t)(r0 + lrow) * 128 + lk * 8;
    const float* hp = h + rowoff;
    const float* bp = buf + rowoff;
    const u16* bph = wt_hi + lrow * 128 + lk * 8;
    const u16* bpl = wt_lo + lrow * 128 + lk * 8;
    floatx4 acc[8];
    #pragma unroll
    for (int j = 0; j < 8; j++) acc[j] = (floatx4){0.f, 0.f, 0.f, 0.f};
    #pragma unroll
    for (int s = 0; s < 4; s++) {
        float4 h0 = *(const float4*)(hp + s * 32);
        float4 h1 = *(const float4*)(hp + s * 32 + 4);
        float4 b0 = *(const float4*)(bp + s * 32);
        float4 b1 = *(const float4*)(bp + s * 32 + 4);
        float hv[8] = {h0.x, h0.y, h0.z, h0.w, h1.x, h1.y, h1.z, h1.w};
        float bvv[8] = {b0.x, b0.y, b0.z, b0.w, b1.x, b1.y, b1.z, b1.w};
        float av[8];
        #pragma unroll
        for (int i = 0; i < 8; i++) {
            int c = lk * 8 + s * 32 + i;
            float m = stats[c] * (1.f / N_NODES);
            float var = stats[128 + c] * (1.f / N_NODES) - m * m;
            float rsn = rsqrtf(var + EPS);
            float val = (bvv[i] - m) * rsn * bng[c] + bnb[c] + hv[i];
            av[i] = fmaxf(val, 0.f);
        }
        short8_t ahi, alo;
        #pragma unroll
        for (int i = 0; i < 8; i++) {
            u16 hb = f2bf(av[i]);
            ahi[i] = (short)hb;
            alo[i] = (short)f2bf(av[i] - bf2f(hb));
        }
        short8_t bh[8], bl[8];
        #pragma unroll
        for (int j = 0; j < 8; j++) {
            bh[j] = *(const short8_t*)(bph + s * 32 + j * 2048);
            bl[j] = *(const short8_t*)(bpl + s * 32 + j * 2048);
        }
        #pragma unroll
        for (int j = 0; j < 8; j++)
            acc[j] = __builtin_amdgcn_mfma_f32_16x16x32_bf16(ahi, bh[j], acc[j], 0, 0, 0);
        #pragma unroll
        for (int j = 0; j < 8; j++)
            acc[j] = __builtin_amdgcn_mfma_f32_16x16x32_bf16(ahi, bl[j], acc[j], 0, 0, 0);
        #pragma unroll
        for (int j = 0; j < 8; j++)
            acc[j] = __builtin_amdgcn_mfma_f32_16x16x32_bf16(alo, bh[j], acc[j], 0, 0, 0);
    }
    // epilogue: y = acc + fb ; LN over each row (r0 + lk*4 + reg)
    float gv[8], bev[8];
    #pragma unroll
    for (int j = 0; j < 8; j++) {
        float fbv = fb[j * 16 + lrow];
        gv[j] = g[j * 16 + lrow];
        bev[j] = be[j * 16 + lrow];
        #pragma unroll
        for (int reg = 0; reg < 4; reg++) acc[j][reg] += fbv;
    }
    float s1[4] = {0.f, 0.f, 0.f, 0.f}, s2[4] = {0.f, 0.f, 0.f, 0.f};
    #pragma unroll
    for (int j = 0; j < 8; j++) {
        #pragma unroll
        for (int reg = 0; reg < 4; reg++) {
            float y = acc[j][reg];
            s1[reg] += y;
            s2[reg] = fmaf(y, y, s2[reg]);
        }
    }
    #pragma unroll
    for (int off = 1; off <= 8; off <<= 1) {
        #pragma unroll
        for (int reg = 0; reg < 4; reg++) {
            s1[reg] += __shfl_xor(s1[reg], off, 64);
            s2[reg] += __shfl_xor(s2[reg], off, 64);
        }
    }
    #pragma unroll
    for (int reg = 0; reg < 4; reg++) {
        float m = s1[reg] * (1.f / 128.f);
        float var = s2[reg] * (1.f / 128.f) - m * m;
        float rs = rsqrtf(var + EPS);
        float* orow = out + (size_t)(r0 + lk * 4 + reg) * 128 + lrow;
        #pragma unroll
        for (int j = 0; j < 8; j++)
            orow[j * 16] = (acc[j][reg] - m) * rs * gv[j] + bev[j];
    }
}

extern "C" void kernel_launch(void* const* d_in, const int* in_sizes, int n_in,
                              void* d_out, int out_size, void* d_ws, size_t ws_size,
                              hipStream_t stream) {
    const float* x      = (const float*)d_in[0];
    const int*   ei     = (const int*)d_in[1];
    const float* ea     = (const float*)d_in[2];
    const float* np_w   = (const float*)d_in[3];
    const float* np_b   = (const float*)d_in[4];
    const float* np_g   = (const float*)d_in[5];
    const float* np_be  = (const float*)d_in[6];
    const float* ep_w   = (const float*)d_in[7];
    const float* ep_b   = (const float*)d_in[8];
    const float* ep_g   = (const float*)d_in[9];
    const float* ep_be  = (const float*)d_in[10];
    const float* gat_w  = (const float*)d_in[11];
    const float* gat_as = (const float*)d_in[12];
    const float* gat_ad = (const float*)d_in[13];
    const float* gat_ew = (const float*)d_in[14];
    const float* gat_ae = (const float*)d_in[15];
    const float* gat_b  = (const float*)d_in[16];
    const float* bn_g   = (const float*)d_in[17];
    const float* bn_b   = (const float*)d_in[18];
    const float* fp_w   = (const float*)d_in[19];
    const float* fp_b   = (const float*)d_in[20];
    const float* fp_g   = (const float*)d_in[21];
    const float* fp_be  = (const float*)d_in[22];
    float* out = (float*)d_out;

    char* ws = (char*)d_ws;
    size_t off = 0;
    auto alloc = [&](size_t bytes) -> void* {
        void* p = ws + off;
        off = (off + bytes + 255) & ~(size_t)255;
        return p;
    };
    float* h      = (float*)alloc((size_t)N_NODES * 128 * 4);
    float* buf    = (float*)alloc((size_t)N_NODES * 128 * 4);
    u16*   xs     = (u16*)alloc((size_t)N_NODES * 128 * 2);
    float* al_s   = (float*)alloc((size_t)N_NODES * 4 * 4);
    float* al_d   = (float*)alloc((size_t)N_NODES * 4 * 4);
    int*   deg    = (int*)alloc((size_t)N_NODES * 4);
    int*   rowptr = (int*)alloc((size_t)(N_NODES + 1) * 4);
    int*   cursor = (int*)alloc((size_t)N_NODES * 4);
    int*   incl   = (int*)alloc((size_t)N_NODES * 4);
    int*   bsum   = (int*)alloc(64 * 4);
    int*   csr_src= (int*)alloc((size_t)N_EDGES * 4);
    float* csr_aE = (float*)alloc((size_t)N_EDGES * 12 * 4);   // SoA [3][E][4]
    float* M      = (float*)alloc(64 * 12 * 4);
    float* stats  = (float*)alloc(256 * 4);
    u16*   wt_hi  = (u16*)alloc((size_t)3 * 16384 * 2);
    u16*   wt_lo  = (u16*)alloc((size_t)3 * 16384 * 2);
    (void)cursor;
    // csr_se aliases buf: buf is first written by k_agg (layer 0), strictly
    // after k_edge_c's last read of csr_se on the same stream.
    int2*  csr_se = (int2*)buf;
    // rank aliases xs: rank written by k_deg, read by k_fill; xs first written
    // by k_gemm_xs_mfma (layer 0), strictly after k_fill.
    int*   rank   = (int*)xs;
    // fp-proj split weights alias incl (scan scratch, dead after k_scan3).
    u16*   wtf_hi = (u16*)incl;
    u16*   wtf_lo = wtf_hi + 16384;

    hipMemsetAsync(deg, 0, (size_t)N_NODES * 4, stream);

    k_M<<<1, 768, 0, stream>>>(gat_ew, gat_ae, M);
    k_convW<<<192, 256, 0, stream>>>(gat_w, wt_hi, wt_lo, 3 * 16384);
    k_node_pre<<<(N_NODES + 3) / 4, 256, 0, stream>>>(x, np_w, np_b, np_g, np_be, h);
    k_deg<<<(N_EDGES + 255) / 256, 256, 0, stream>>>(ei + N_EDGES, deg, rank);
    int nblk = (N_NODES + 1023) / 1024;
    k_scan1<<<nblk, 1024, 0, stream>>>(deg, incl, bsum);
    k_scan2<<<1, 64, 0, stream>>>(bsum, nblk);
    k_scan3<<<nblk, 1024, 0, stream>>>(incl, bsum, rowptr);
    // incl is dead from here on; convert fp_w into its space.
    k_convW<<<64, 256, 0, stream>>>(fp_w, wtf_hi, wtf_lo, 16384);
    k_fill<<<(N_EDGES + 255) / 256, 256, 0, stream>>>(ei, rowptr, rank, csr_se);
    k_edge_c<<<(N_EDGES + 255) / 256, 256, 0, stream>>>(csr_se, ea, ep_w, ep_b, ep_g,
                                                        ep_be, M, csr_src, csr_aE);

    for (int l = 0; l < 3; l++) {
        // l>0: fuse previous layer's BN-apply (stats of layer l-1) into A-load.
        k_gemm_xs_mfma<<<(3125 + 3) / 4, 256, 0, stream>>>(
            h, buf, stats, bn_g + (l > 0 ? (l - 1) * 128 : 0),
            bn_b + (l > 0 ? (l - 1) * 128 : 0),
            wt_hi + (size_t)l * 16384, wt_lo + (size_t)l * 16384, xs, l > 0 ? 1 : 0);
        k_al<<<(N_NODES * 4 + 255) / 256, 256, 0, stream>>>(xs, gat_as + l * 128,
                                                            gat_ad + l * 128, al_s, al_d);
        hipMemsetAsync(stats, 0, 256 * 4, stream);
        k_agg<<<(N_NODES + 3) / 4, 256, 0, stream>>>(rowptr, csr_src,
                                                     csr_aE + (size_t)l * N_EDGES * 4,
                                                     al_s, al_d, xs, gat_b + l * 128, buf);
        k_bn_stats<<<256, 256, 0, stream>>>(buf, stats);
    }
    // final: fuse layer-2 BN-apply into the fp GEMM A-load.
    k_gemm_fp_mfma<<<(3125 + 3) / 4, 256, 0, stream>>>(
        h, buf, stats, bn_g + 2 * 128, bn_b + 2 * 128,
        wtf_hi, wtf_lo, fp_b, fp_g, fp_be, out);
}

// Round 12
// 660.339 us; speedup vs baseline: 1.5183x; 1.0193x over previous
//
#include <hip/hip_runtime.h>
#include <hip/hip_bf16.h>
#include <math.h>

#define N_NODES 50000
#define N_EDGES 800000
#define EPS 1e-5f
#define SLOPE 0.2f

typedef unsigned int u32;
typedef unsigned short u16;
typedef float floatx4 __attribute__((ext_vector_type(4)));
typedef short short8_t __attribute__((ext_vector_type(8)));

__device__ __forceinline__ float bf2f(u16 v) {
    u32 u = ((u32)v) << 16;
    return __uint_as_float(u);
}
__device__ __forceinline__ u16 f2bf(float f) {
    u32 u = __float_as_uint(f);
    u32 r = (u + 0x7fffu + ((u >> 16) & 1u)) >> 16;  // RNE
    return (u16)r;
}
__device__ __forceinline__ float lo_bf(u32 v) { return __uint_as_float(v << 16); }
__device__ __forceinline__ float hi_bf(u32 v) { return __uint_as_float(v & 0xffff0000u); }
__device__ __forceinline__ float wred(float v) {
    #pragma unroll
    for (int off = 32; off > 0; off >>= 1) v += __shfl_xor(v, off, 64);
    return v;
}

// ---- fused prologue: blocks 0..191 split-transpose gat_w; 192..194 compute M ----
__global__ void k_prep(const float* __restrict__ w, u16* __restrict__ hi,
                       u16* __restrict__ lo, const float* __restrict__ ew,
                       const float* __restrict__ ae, float* __restrict__ M) {
    int b = blockIdx.x;
    if (b < 192) {
        int i = b * 256 + threadIdx.x;          // < 49152 = 3*16384 exact
        int l = i >> 14, r = i & 16383;
        int n = r >> 7, k = r & 127;
        float f = w[(size_t)l * 16384 + k * 128 + n];
        u16 hb = f2bf(f);
        hi[i] = hb;
        lo[i] = f2bf(f - bf2f(hb));
    } else {
        int t = (b - 192) * 256 + threadIdx.x;
        if (t >= 768) return;
        int k = t / 12, j = t % 12;
        int l = j >> 2, h = j & 3;
        const float* ewp = ew + l * 8192 + k * 128 + h * 32;
        const float* aep = ae + l * 128 + h * 32;
        float s = 0.f;
        #pragma unroll
        for (int c = 0; c < 32; c++) s += ewp[c] * aep[c];
        M[k * 12 + j] = s;
    }
}

// ---- node preprocess: h = relu(LN(x @ np_w + np_b)) ; wave per node ----
__global__ __launch_bounds__(256) void k_node_pre(
        const float* __restrict__ x, const float* __restrict__ w,
        const float* __restrict__ b, const float* __restrict__ g,
        const float* __restrict__ be, float* __restrict__ h) {
    int wave = threadIdx.x >> 6, lane = threadIdx.x & 63;
    int n = blockIdx.x * 4 + wave;
    if (n >= N_NODES) return;
    const float* xr = x + (size_t)n * 16;
    float xv[16];
    #pragma unroll
    for (int k = 0; k < 16; k++) xv[k] = xr[k];
    int c0 = lane, c1 = lane + 64;
    float a0 = b[c0], a1 = b[c1];
    #pragma unroll
    for (int k = 0; k < 16; k++) {
        a0 = fmaf(xv[k], w[k * 128 + c0], a0);
        a1 = fmaf(xv[k], w[k * 128 + c1], a1);
    }
    float m = wred(a0 + a1) * (1.f / 128.f);
    float d0 = a0 - m, d1 = a1 - m;
    float v = wred(d0 * d0 + d1 * d1) * (1.f / 128.f);
    float rs = rsqrtf(v + EPS);
    float o0 = d0 * rs * g[c0] + be[c0];
    float o1 = d1 * rs * g[c1] + be[c1];
    h[(size_t)n * 128 + c0] = fmaxf(o0, 0.f);
    h[(size_t)n * 128 + c1] = fmaxf(o1, 0.f);
}

// ---- degree count + within-row rank (atomic return value, coalesced write) ----
__global__ void k_deg(const int* __restrict__ dst, int* __restrict__ deg,
                      int* __restrict__ rank) {
    int e = blockIdx.x * 256 + threadIdx.x;
    if (e < N_EDGES) rank[e] = atomicAdd(&deg[dst[e]], 1);
}

// ---- scan phase 1: per-block inclusive scan + raw block sums ----
__global__ void k_scan1(const int* __restrict__ deg, int* __restrict__ incl,
                        int* __restrict__ bsum) {
    __shared__ int lds[1024];
    int i = blockIdx.x * 1024 + threadIdx.x;
    int v = (i < N_NODES) ? deg[i] : 0;
    lds[threadIdx.x] = v;
    __syncthreads();
    for (int off = 1; off < 1024; off <<= 1) {
        int t = (threadIdx.x >= off) ? lds[threadIdx.x - off] : 0;
        __syncthreads();
        lds[threadIdx.x] += t;
        __syncthreads();
    }
    if (i < N_NODES) incl[i] = lds[threadIdx.x];
    if (threadIdx.x == 1023) bsum[blockIdx.x] = lds[1023];
}
// ---- scan phase 2+3 fused: each block computes its own bsum prefix ----
__global__ void k_scan3(const int* __restrict__ incl, const int* __restrict__ bsum,
                        int* __restrict__ rowptr) {
    __shared__ int base_s;
    if (threadIdx.x == 0) {
        int acc = 0;
        for (int i = 0; i < (int)blockIdx.x; i++) acc += bsum[i];
        base_s = acc;
    }
    __syncthreads();
    int i = blockIdx.x * 1024 + threadIdx.x;
    if (i < N_NODES) rowptr[i + 1] = incl[i] + base_s;
    if (i == 0) rowptr[0] = 0;
}

// ---- CSR slot fill (blocks 0..3124) + fp-weight split-transpose (3125..3188) ----
__global__ void k_fill(const int* __restrict__ ei, const int* __restrict__ rowptr,
                       const int* __restrict__ rank, int2* __restrict__ csr_se,
                       const float* __restrict__ fw, u16* __restrict__ fhi,
                       u16* __restrict__ flo) {
    int b = blockIdx.x;
    if (b < 3125) {
        int e = b * 256 + threadIdx.x;
        if (e >= N_EDGES) return;
        int src = ei[e], dst = ei[N_EDGES + e];
        int slot = rowptr[dst] + rank[e];
        csr_se[slot] = make_int2(src, e);
    } else {
        int i = (b - 3125) * 256 + threadIdx.x;   // < 16384 exact (64 blocks)
        int n = i >> 7, k = i & 127;
        float f = fw[k * 128 + n];
        u16 hb = f2bf(f);
        fhi[i] = hb;
        flo[i] = f2bf(f - bf2f(hb));
    }
}

// ---- edge preprocess + alphaE over SLOTS: 1 edge/thread, float4-packed ----
__global__ __launch_bounds__(256) void k_edge_c(
        const int2* __restrict__ csr_se, const float* __restrict__ ea,
        const float* __restrict__ epw, const float* __restrict__ epb,
        const float* __restrict__ epg, const float* __restrict__ epbe,
        const float* __restrict__ M, int* __restrict__ csr_src,
        float* __restrict__ csr_aE) {
    __shared__ floatx4 sW4[128], sM4[192], sB4[16], sG4[16], sBe4[16];
    int tid = threadIdx.x;
    if (tid < 128) sW4[tid] = ((const floatx4*)epw)[tid];
    if (tid < 192) sM4[tid] = ((const floatx4*)M)[tid];
    if (tid < 16) sB4[tid] = ((const floatx4*)epb)[tid];
    if (tid >= 32 && tid < 48) sG4[tid - 32] = ((const floatx4*)epg)[tid - 32];
    if (tid >= 64 && tid < 80) sBe4[tid - 64] = ((const floatx4*)epbe)[tid - 64];
    __syncthreads();
    int s = blockIdx.x * 256 + tid;
    if (s >= N_EDGES) return;
    int2 se = csr_se[s];
    int src = se.x, e = se.y;
    float4 x0 = *(const float4*)(ea + (size_t)e * 8);
    float4 x1 = *(const float4*)(ea + (size_t)e * 8 + 4);
    float xa[8] = {x0.x, x0.y, x0.z, x0.w, x1.x, x1.y, x1.z, x1.w};
    floatx4 v4[16];
    floatx4 sum4 = {0.f, 0.f, 0.f, 0.f};
    #pragma unroll
    for (int c4 = 0; c4 < 16; c4++) {
        floatx4 a = sB4[c4];
        #pragma unroll
        for (int k = 0; k < 8; k++) a += xa[k] * sW4[k * 16 + c4];
        v4[c4] = a;
        sum4 += a;
    }
    float m = (sum4[0] + sum4[1] + sum4[2] + sum4[3]) * (1.f / 64.f);
    floatx4 var4 = {0.f, 0.f, 0.f, 0.f};
    #pragma unroll
    for (int c4 = 0; c4 < 16; c4++) { floatx4 d = v4[c4] - m; var4 += d * d; }
    float rs = rsqrtf((var4[0] + var4[1] + var4[2] + var4[3]) * (1.f / 64.f) + EPS);
    #pragma unroll
    for (int c4 = 0; c4 < 16; c4++) {
        floatx4 o = (v4[c4] - m) * rs * sG4[c4] + sBe4[c4];
        #pragma unroll
        for (int p = 0; p < 4; p++) v4[c4][p] = fmaxf(o[p], 0.f);
    }
    floatx4 aE0 = {0.f, 0.f, 0.f, 0.f};
    floatx4 aE1 = {0.f, 0.f, 0.f, 0.f};
    floatx4 aE2 = {0.f, 0.f, 0.f, 0.f};
    #pragma unroll
    for (int c = 0; c < 64; c++) {
        float vc = v4[c >> 2][c & 3];
        aE0 += vc * sM4[c * 3 + 0];
        aE1 += vc * sM4[c * 3 + 1];
        aE2 += vc * sM4[c * 3 + 2];
    }
    csr_src[s] = src;
    *(floatx4*)(csr_aE + ((size_t)0 * N_EDGES + s) * 4) = aE0;
    *(floatx4*)(csr_aE + ((size_t)1 * N_EDGES + s) * 4) = aE1;
    *(floatx4*)(csr_aE + ((size_t)2 * N_EDGES + s) * 4) = aE2;
}

// ---- GEMM xs = h @ W via MFMA (3-term bf16 split), optional fused BN-apply ----
__global__ __launch_bounds__(256) void k_gemm_xs_mfma(
        float* __restrict__ h, const float* __restrict__ buf,
        const float* __restrict__ stats, const float* __restrict__ bng,
        const float* __restrict__ bnb, const u16* __restrict__ wt_hi,
        const u16* __restrict__ wt_lo, u16* __restrict__ xs, int fuse) {
    int wave = threadIdx.x >> 6, lane = threadIdx.x & 63;
    int r0 = (blockIdx.x * 4 + wave) * 16;
    if (r0 >= N_NODES) return;
    int lrow = lane & 15, lk = lane >> 4;
    size_t rowoff = (size_t)(r0 + lrow) * 128 + lk * 8;
    float* hp = h + rowoff;
    const float* bp = buf + rowoff;
    const u16* bph = wt_hi + lrow * 128 + lk * 8;
    const u16* bpl = wt_lo + lrow * 128 + lk * 8;
    floatx4 acc[8];
    #pragma unroll
    for (int j = 0; j < 8; j++) acc[j] = (floatx4){0.f, 0.f, 0.f, 0.f};
    #pragma unroll
    for (int s = 0; s < 4; s++) {
        float av[8];
        float4 h0 = *(const float4*)(hp + s * 32);
        float4 h1 = *(const float4*)(hp + s * 32 + 4);
        float hv[8] = {h0.x, h0.y, h0.z, h0.w, h1.x, h1.y, h1.z, h1.w};
        if (fuse) {
            float4 b0 = *(const float4*)(bp + s * 32);
            float4 b1 = *(const float4*)(bp + s * 32 + 4);
            float bv[8] = {b0.x, b0.y, b0.z, b0.w, b1.x, b1.y, b1.z, b1.w};
            #pragma unroll
            for (int i = 0; i < 8; i++) {
                int c = lk * 8 + s * 32 + i;
                float m = stats[c] * (1.f / N_NODES);
                float var = stats[128 + c] * (1.f / N_NODES) - m * m;
                float rsn = rsqrtf(var + EPS);
                float val = (bv[i] - m) * rsn * bng[c] + bnb[c] + hv[i];
                av[i] = fmaxf(val, 0.f);
            }
            float4 w0, w1;
            w0.x = av[0]; w0.y = av[1]; w0.z = av[2]; w0.w = av[3];
            w1.x = av[4]; w1.y = av[5]; w1.z = av[6]; w1.w = av[7];
            *(float4*)(hp + s * 32) = w0;
            *(float4*)(hp + s * 32 + 4) = w1;
        } else {
            #pragma unroll
            for (int i = 0; i < 8; i++) av[i] = hv[i];
        }
        short8_t ahi, alo;
        #pragma unroll
        for (int i = 0; i < 8; i++) {
            u16 hb = f2bf(av[i]);
            ahi[i] = (short)hb;
            alo[i] = (short)f2bf(av[i] - bf2f(hb));
        }
        short8_t bh[8], bl[8];
        #pragma unroll
        for (int j = 0; j < 8; j++) {
            bh[j] = *(const short8_t*)(bph + s * 32 + j * 2048);
            bl[j] = *(const short8_t*)(bpl + s * 32 + j * 2048);
        }
        #pragma unroll
        for (int j = 0; j < 8; j++)
            acc[j] = __builtin_amdgcn_mfma_f32_16x16x32_bf16(ahi, bh[j], acc[j], 0, 0, 0);
        #pragma unroll
        for (int j = 0; j < 8; j++)
            acc[j] = __builtin_amdgcn_mfma_f32_16x16x32_bf16(ahi, bl[j], acc[j], 0, 0, 0);
        #pragma unroll
        for (int j = 0; j < 8; j++)
            acc[j] = __builtin_amdgcn_mfma_f32_16x16x32_bf16(alo, bh[j], acc[j], 0, 0, 0);
    }
    // D: row = r0 + lk*4 + reg, col = j*16 + lrow
    u16* orow = xs + (size_t)(r0 + lk * 4) * 128 + lrow;
    #pragma unroll
    for (int j = 0; j < 8; j++) {
        #pragma unroll
        for (int reg = 0; reg < 4; reg++)
            orow[(size_t)reg * 128 + j * 16] = f2bf(acc[j][reg]);
    }
}

// ---- al_s / al_d per (node, head), vectorized xs loads ----
__global__ void k_al(const u16* __restrict__ xs, const float* __restrict__ as_,
                     const float* __restrict__ ad_, float* __restrict__ al_s,
                     float* __restrict__ al_d) {
    int t = blockIdx.x * 256 + threadIdx.x;
    if (t >= N_NODES * 4) return;
    int n = t >> 2, hh = t & 3;
    const uint4* xp = (const uint4*)(xs + (size_t)n * 128 + hh * 32);
    const float* app = as_ + hh * 32;
    const float* dpp = ad_ + hh * 32;
    float s = 0.f, d = 0.f;
    #pragma unroll
    for (int q = 0; q < 4; q++) {
        uint4 v = xp[q];
        u32 wv[4] = {v.x, v.y, v.z, v.w};
        #pragma unroll
        for (int p = 0; p < 4; p++) {
            int c = q * 8 + p * 2;
            float fl = lo_bf(wv[p]), fh = hi_bf(wv[p]);
            s = fmaf(fl, app[c], s); s = fmaf(fh, app[c + 1], s);
            d = fmaf(fl, dpp[c], d); d = fmaf(fh, dpp[c + 1], d);
        }
    }
    al_s[t] = s; al_d[t] = d;
}

// ---- GAT aggregation: wave per node, lane owns channel pair (2l, 2l+1) ----
__global__ __launch_bounds__(256) void k_agg(
        const int* __restrict__ rowptr, const int* __restrict__ csr_src,
        const float* __restrict__ aEl, const float* __restrict__ al_s,
        const float* __restrict__ al_d, const u16* __restrict__ xs,
        const float* __restrict__ bias, float* __restrict__ outp) {
    int lane = threadIdx.x & 63;
    int n = __builtin_amdgcn_readfirstlane(blockIdx.x * 4 + (threadIdx.x >> 6));
    if (n >= N_NODES) return;
    int row = rowptr[n], end = rowptr[n + 1];
    int hh = lane >> 4;
    const u32* xsw = (const u32*)xs;
    float ald = al_d[n * 4 + hh];
    float asn = al_s[n * 4 + hh];
    u32 xnp = xsw[(size_t)n * 64 + lane];
    float acc0 = 0.f, acc1 = 0.f, ssum = 0.f, aes = 0.f;
    int slot = row;
    for (; slot + 8 <= end; slot += 8) {
        int sv[8]; float ae[8], asv[8]; u32 xv[8];
        #pragma unroll
        for (int i = 0; i < 8; i++) sv[i] = csr_src[slot + i];
        #pragma unroll
        for (int i = 0; i < 8; i++) ae[i] = aEl[(size_t)(slot + i) * 4 + hh];
        #pragma unroll
        for (int i = 0; i < 8; i++) asv[i] = al_s[sv[i] * 4 + hh];
        #pragma unroll
        for (int i = 0; i < 8; i++) xv[i] = xsw[(size_t)sv[i] * 64 + lane];
        #pragma unroll
        for (int i = 0; i < 8; i++) {
            aes += ae[i];
            float a = asv[i] + ald + ae[i]; a = (a >= 0.f) ? a : SLOPE * a;
            float ev = __expf(a);
            ssum += ev;
            acc0 = fmaf(ev, lo_bf(xv[i]), acc0);
            acc1 = fmaf(ev, hi_bf(xv[i]), acc1);
        }
    }
    for (; slot + 4 <= end; slot += 4) {
        int sv[4]; float ae[4], asv[4]; u32 xv[4];
        #pragma unroll
        for (int i = 0; i < 4; i++) sv[i] = csr_src[slot + i];
        #pragma unroll
        for (int i = 0; i < 4; i++) ae[i] = aEl[(size_t)(slot + i) * 4 + hh];
        #pragma unroll
        for (int i = 0; i < 4; i++) asv[i] = al_s[sv[i] * 4 + hh];
        #pragma unroll
        for (int i = 0; i < 4; i++) xv[i] = xsw[(size_t)sv[i] * 64 + lane];
        #pragma unroll
        for (int i = 0; i < 4; i++) {
            aes += ae[i];
            float a = asv[i] + ald + ae[i]; a = (a >= 0.f) ? a : SLOPE * a;
            float ev = __expf(a);
            ssum += ev;
            acc0 = fmaf(ev, lo_bf(xv[i]), acc0);
            acc1 = fmaf(ev, hi_bf(xv[i]), acc1);
        }
    }
    for (; slot < end; slot++) {
        int sA = csr_src[slot];
        float aeA = aEl[(size_t)slot * 4 + hh];
        float asA = al_s[sA * 4 + hh];
        u32 xA = xsw[(size_t)sA * 64 + lane];
        aes += aeA;
        float aA = asA + ald + aeA; aA = (aA >= 0.f) ? aA : SLOPE * aA;
        float eA = __expf(aA);
        ssum += eA;
        acc0 = fmaf(eA, lo_bf(xA), acc0); acc1 = fmaf(eA, hi_bf(xA), acc1);
    }
    // self-loop (PyG add_self_loops, fill_value='mean'): aE = mean over row
    float dinv = 1.f / fmaxf((float)(end - row), 1.f);
    float sa = asn + ald + aes * dinv; sa = (sa >= 0.f) ? sa : SLOPE * sa;
    float e = __expf(sa);
    ssum += e;
    acc0 = fmaf(e, lo_bf(xnp), acc0); acc1 = fmaf(e, hi_bf(xnp), acc1);
    float2 bv = *(const float2*)(bias + lane * 2);
    float2 o;
    o.x = acc0 / ssum + bv.x;
    o.y = acc1 / ssum + bv.y;
    *(float2*)(outp + (size_t)n * 128 + lane * 2) = o;
}

// ---- BN stats (sum, sumsq per channel) ----
__global__ void k_bn_stats(const float* __restrict__ x, float* __restrict__ stats) {
    __shared__ float lds[512];
    int t = threadIdx.x;
    int c = t & 127, half = t >> 7;
    float s = 0.f, q = 0.f;
    for (int n = blockIdx.x * 2 + half; n < N_NODES; n += gridDim.x * 2) {
        float v = x[(size_t)n * 128 + c];
        s += v; q = fmaf(v, v, q);
    }
    lds[t] = s; lds[256 + t] = q;
    __syncthreads();
    if (t < 128) {
        atomicAdd(&stats[c], lds[t] + lds[t + 128]);
        atomicAdd(&stats[128 + c], lds[256 + t] + lds[256 + t + 128]);
    }
}

// ---- final proj: fused BN-apply + MFMA GEMM (3-term bf16 split) + bias + LN ----
__global__ __launch_bounds__(256) void k_gemm_fp_mfma(
        const float* __restrict__ h, const float* __restrict__ buf,
        const float* __restrict__ stats, const float* __restrict__ bng,
        const float* __restrict__ bnb, const u16* __restrict__ wt_hi,
        const u16* __restrict__ wt_lo, const float* __restrict__ fb,
        const float* __restrict__ g, const float* __restrict__ be,
        float* __restrict__ out) {
    int wave = threadIdx.x >> 6, lane = threadIdx.x & 63;
    int r0 = (blockIdx.x * 4 + wave) * 16;
    if (r0 >= N_NODES) return;
    int lrow = lane & 15, lk = lane >> 4;
    size_t rowoff = (size_t)(r0 + lrow) * 128 + lk * 8;
    const float* hp = h + rowoff;
    const float* bp = buf + rowoff;
    const u16* bph = wt_hi + lrow * 128 + lk * 8;
    const u16* bpl = wt_lo + lrow * 128 + lk * 8;
    floatx4 acc[8];
    #pragma unroll
    for (int j = 0; j < 8; j++) acc[j] = (floatx4){0.f, 0.f, 0.f, 0.f};
    #pragma unroll
    for (int s = 0; s < 4; s++) {
        float4 h0 = *(const float4*)(hp + s * 32);
        float4 h1 = *(const float4*)(hp + s * 32 + 4);
        float4 b0 = *(const float4*)(bp + s * 32);
        float4 b1 = *(const float4*)(bp + s * 32 + 4);
        float hv[8] = {h0.x, h0.y, h0.z, h0.w, h1.x, h1.y, h1.z, h1.w};
        float bvv[8] = {b0.x, b0.y, b0.z, b0.w, b1.x, b1.y, b1.z, b1.w};
        float av[8];
        #pragma unroll
        for (int i = 0; i < 8; i++) {
            int c = lk * 8 + s * 32 + i;
            float m = stats[c] * (1.f / N_NODES);
            float var = stats[128 + c] * (1.f / N_NODES) - m * m;
            float rsn = rsqrtf(var + EPS);
            float val = (bvv[i] - m) * rsn * bng[c] + bnb[c] + hv[i];
            av[i] = fmaxf(val, 0.f);
        }
        short8_t ahi, alo;
        #pragma unroll
        for (int i = 0; i < 8; i++) {
            u16 hb = f2bf(av[i]);
            ahi[i] = (short)hb;
            alo[i] = (short)f2bf(av[i] - bf2f(hb));
        }
        short8_t bh[8], bl[8];
        #pragma unroll
        for (int j = 0; j < 8; j++) {
            bh[j] = *(const short8_t*)(bph + s * 32 + j * 2048);
            bl[j] = *(const short8_t*)(bpl + s * 32 + j * 2048);
        }
        #pragma unroll
        for (int j = 0; j < 8; j++)
            acc[j] = __builtin_amdgcn_mfma_f32_16x16x32_bf16(ahi, bh[j], acc[j], 0, 0, 0);
        #pragma unroll
        for (int j = 0; j < 8; j++)
            acc[j] = __builtin_amdgcn_mfma_f32_16x16x32_bf16(ahi, bl[j], acc[j], 0, 0, 0);
        #pragma unroll
        for (int j = 0; j < 8; j++)
            acc[j] = __builtin_amdgcn_mfma_f32_16x16x32_bf16(alo, bh[j], acc[j], 0, 0, 0);
    }
    // epilogue: y = acc + fb ; LN over each row (r0 + lk*4 + reg)
    float gv[8], bev[8];
    #pragma unroll
    for (int j = 0; j < 8; j++) {
        float fbv = fb[j * 16 + lrow];
        gv[j] = g[j * 16 + lrow];
        bev[j] = be[j * 16 + lrow];
        #pragma unroll
        for (int reg = 0; reg < 4; reg++) acc[j][reg] += fbv;
    }
    float s1[4] = {0.f, 0.f, 0.f, 0.f}, s2[4] = {0.f, 0.f, 0.f, 0.f};
    #pragma unroll
    for (int j = 0; j < 8; j++) {
        #pragma unroll
        for (int reg = 0; reg < 4; reg++) {
            float y = acc[j][reg];
            s1[reg] += y;
            s2[reg] = fmaf(y, y, s2[reg]);
        }
    }
    #pragma unroll
    for (int off = 1; off <= 8; off <<= 1) {
        #pragma unroll
        for (int reg = 0; reg < 4; reg++) {
            s1[reg] += __shfl_xor(s1[reg], off, 64);
            s2[reg] += __shfl_xor(s2[reg], off, 64);
        }
    }
    #pragma unroll
    for (int reg = 0; reg < 4; reg++) {
        float m = s1[reg] * (1.f / 128.f);
        float var = s2[reg] * (1.f / 128.f) - m * m;
        float rs = rsqrtf(var + EPS);
        float* orow = out + (size_t)(r0 + lk * 4 + reg) * 128 + lrow;
        #pragma unroll
        for (int j = 0; j < 8; j++)
            orow[j * 16] = (acc[j][reg] - m) * rs * gv[j] + bev[j];
    }
}

extern "C" void kernel_launch(void* const* d_in, const int* in_sizes, int n_in,
                              void* d_out, int out_size, void* d_ws, size_t ws_size,
                              hipStream_t stream) {
    const float* x      = (const float*)d_in[0];
    const int*   ei     = (const int*)d_in[1];
    const float* ea     = (const float*)d_in[2];
    const float* np_w   = (const float*)d_in[3];
    const float* np_b   = (const float*)d_in[4];
    const float* np_g   = (const float*)d_in[5];
    const float* np_be  = (const float*)d_in[6];
    const float* ep_w   = (const float*)d_in[7];
    const float* ep_b   = (const float*)d_in[8];
    const float* ep_g   = (const float*)d_in[9];
    const float* ep_be  = (const float*)d_in[10];
    const float* gat_w  = (const float*)d_in[11];
    const float* gat_as = (const float*)d_in[12];
    const float* gat_ad = (const float*)d_in[13];
    const float* gat_ew = (const float*)d_in[14];
    const float* gat_ae = (const float*)d_in[15];
    const float* gat_b  = (const float*)d_in[16];
    const float* bn_g   = (const float*)d_in[17];
    const float* bn_b   = (const float*)d_in[18];
    const float* fp_w   = (const float*)d_in[19];
    const float* fp_b   = (const float*)d_in[20];
    const float* fp_g   = (const float*)d_in[21];
    const float* fp_be  = (const float*)d_in[22];
    float* out = (float*)d_out;

    char* ws = (char*)d_ws;
    size_t off = 0;
    auto alloc = [&](size_t bytes) -> void* {
        void* p = ws + off;
        off = (off + bytes + 255) & ~(size_t)255;
        return p;
    };
    // Workspace layout IDENTICAL to the passing round-8/11 kernel (no growth).
    float* h      = (float*)alloc((size_t)N_NODES * 128 * 4);
    float* buf    = (float*)alloc((size_t)N_NODES * 128 * 4);
    u16*   xs     = (u16*)alloc((size_t)N_NODES * 128 * 2);
    float* al_s   = (float*)alloc((size_t)N_NODES * 4 * 4);
    float* al_d   = (float*)alloc((size_t)N_NODES * 4 * 4);
    int*   deg    = (int*)alloc((size_t)N_NODES * 4);
    int*   rowptr = (int*)alloc((size_t)(N_NODES + 1) * 4);
    int*   cursor = (int*)alloc((size_t)N_NODES * 4);
    int*   incl   = (int*)alloc((size_t)N_NODES * 4);
    int*   bsum   = (int*)alloc(64 * 4);
    int*   csr_src= (int*)alloc((size_t)N_EDGES * 4);
    float* csr_aE = (float*)alloc((size_t)N_EDGES * 12 * 4);   // SoA [3][E][4]
    float* M      = (float*)alloc(64 * 12 * 4);
    float* stats  = (float*)alloc(256 * 4);
    u16*   wt_hi  = (u16*)alloc((size_t)3 * 16384 * 2);
    u16*   wt_lo  = (u16*)alloc((size_t)3 * 16384 * 2);
    (void)stats;
    // csr_se aliases buf: buf is first written by k_agg (layer 0), strictly
    // after k_edge_c's last read of csr_se on the same stream.
    int2*  csr_se = (int2*)buf;
    // rank aliases xs: rank written by k_deg, read by k_fill; xs first written
    // by k_gemm_xs_mfma (layer 0), strictly after k_fill.
    int*   rank   = (int*)xs;
    // fp-proj split weights alias incl (scan scratch, dead after k_scan3).
    u16*   wtf_hi = (u16*)incl;
    u16*   wtf_lo = wtf_hi + 16384;
    // 3 per-layer BN-stats buffers alias cursor (200KB, otherwise dead).
    float* stats3 = (float*)cursor;

    hipMemsetAsync(deg, 0, (size_t)N_NODES * 4, stream);
    hipMemsetAsync(stats3, 0, 3 * 256 * 4, stream);

    k_prep<<<195, 256, 0, stream>>>(gat_w, wt_hi, wt_lo, gat_ew, gat_ae, M);
    k_node_pre<<<(N_NODES + 3) / 4, 256, 0, stream>>>(x, np_w, np_b, np_g, np_be, h);
    k_deg<<<(N_EDGES + 255) / 256, 256, 0, stream>>>(ei + N_EDGES, deg, rank);
    int nblk = (N_NODES + 1023) / 1024;
    k_scan1<<<nblk, 1024, 0, stream>>>(deg, incl, bsum);
    k_scan3<<<nblk, 1024, 0, stream>>>(incl, bsum, rowptr);
    // k_fill blocks 0..3124 scatter csr_se; 3125..3188 convert fp_w into the
    // now-dead incl space (runs strictly after k_scan3's last incl read).
    k_fill<<<3189, 256, 0, stream>>>(ei, rowptr, rank, csr_se, fp_w, wtf_hi, wtf_lo);
    k_edge_c<<<(N_EDGES + 255) / 256, 256, 0, stream>>>(csr_se, ea, ep_w, ep_b, ep_g,
                                                        ep_be, M, csr_src, csr_aE);

    for (int l = 0; l < 3; l++) {
        // l>0: fuse previous layer's BN-apply (stats of layer l-1) into A-load.
        k_gemm_xs_mfma<<<(3125 + 3) / 4, 256, 0, stream>>>(
            h, buf, stats3 + (l > 0 ? (l - 1) * 256 : 0),
            bn_g + (l > 0 ? (l - 1) * 128 : 0),
            bn_b + (l > 0 ? (l - 1) * 128 : 0),
            wt_hi + (size_t)l * 16384, wt_lo + (size_t)l * 16384, xs, l > 0 ? 1 : 0);
        k_al<<<(N_NODES * 4 + 255) / 256, 256, 0, stream>>>(xs, gat_as + l * 128,
                                                            gat_ad + l * 128, al_s, al_d);
        k_agg<<<(N_NODES + 3) / 4, 256, 0, stream>>>(rowptr, csr_src,
                                                     csr_aE + (size_t)l * N_EDGES * 4,
                                                     al_s, al_d, xs, gat_b + l * 128, buf);
        k_bn_stats<<<256, 256, 0, stream>>>(buf, stats3 + l * 256);
    }
    // final: fuse layer-2 BN-apply into the fp GEMM A-load.
    k_gemm_fp_mfma<<<(3125 + 3) / 4, 256, 0, stream>>>(
        h, buf, stats3 + 2 * 256, bn_g + 2 * 128, bn_b + 2 * 128,
        wtf_hi, wtf_lo, fp_b, fp_g, fp_be, out);
}